// Round 10
// baseline (188.782 us; speedup 1.0000x reference)
//
#include <hip/hip_runtime.h>
#include <hip/hip_bf16.h>

#define D_FEAT 64
#define OVF_CAP 65536
#define EB 8192              // edges per block in the multisplit
#define NBMAX 1024           // max coarse buckets (n <= 256K)

typedef unsigned int uint32;

__device__ inline float blo(uint32 u) { return __uint_as_float(u << 16); }
__device__ inline float bhi(uint32 u) { return __uint_as_float(u & 0xffff0000u); }
__device__ inline float dinv(int d) { return (d > 0) ? rsqrtf((float)d) : 0.0f; }
__device__ inline uint32 pack_bf16x2(float a, float b) {
    __hip_bfloat16 ba = __float2bfloat16(a);
    __hip_bfloat16 bb = __float2bfloat16(b);
    uint32 ua = *reinterpret_cast<unsigned short*>(&ba);
    uint32 ub = *reinterpret_cast<unsigned short*>(&bb);
    return ua | (ub << 16);
}

// ---- phase 1: per-block LDS histogram over coarse buckets ----
__global__ __launch_bounds__(256) void k_hist(const int* __restrict__ col,
                                              int* __restrict__ histT,
                                              int E, int B, int nb) {
    __shared__ int h[NBMAX];
    for (int i = threadIdx.x; i < nb; i += 256) h[i] = 0;
    __syncthreads();
    const int b = blockIdx.x;
    const int s = b * EB;
    const int e = (s + EB < E) ? s + EB : E;
    for (int i = s + threadIdx.x; i < e; i += 256)
        atomicAdd(&h[col[i] >> 8], 1);
    __syncthreads();
    for (int k = threadIdx.x; k < nb; k += 256)
        histT[(size_t)k * B + b] = h[k];            // bucket-major for the scan
}

// ---- phase 2a: per-bucket exclusive scan over blocks (one block per bucket) ----
__global__ __launch_bounds__(512) void k_colscan(int* __restrict__ histT,
                                                 int* __restrict__ total, int B) {
    __shared__ int sh[512];
    const int k = blockIdx.x;
    int v = (threadIdx.x < B) ? histT[(size_t)k * B + threadIdx.x] : 0;
    sh[threadIdx.x] = v;
    __syncthreads();
    for (int off = 1; off < 512; off <<= 1) {
        int t = (threadIdx.x >= off) ? sh[threadIdx.x - off] : 0;
        __syncthreads();
        sh[threadIdx.x] += t;
        __syncthreads();
    }
    int incl = sh[threadIdx.x];
    if (threadIdx.x < B) histT[(size_t)k * B + threadIdx.x] = incl - v;  // exclusive
    if (threadIdx.x == 511) total[k] = incl;
}

// ---- phase 2b: scan bucket totals -> bstart; zero ovf_cnt ----
__global__ __launch_bounds__(1024) void k_tinyscan(const int* __restrict__ total,
                                                   int* __restrict__ bstart,
                                                   int* __restrict__ ovf_cnt, int nb) {
    __shared__ int sh[1024];
    int v = (threadIdx.x < nb) ? total[threadIdx.x] : 0;
    sh[threadIdx.x] = v;
    __syncthreads();
    for (int off = 1; off < 1024; off <<= 1) {
        int t = (threadIdx.x >= off) ? sh[threadIdx.x - off] : 0;
        __syncthreads();
        sh[threadIdx.x] += t;
        __syncthreads();
    }
    if (threadIdx.x < nb) bstart[threadIdx.x] = sh[threadIdx.x] - v;
    if (threadIdx.x == nb - 1) bstart[nb] = sh[threadIdx.x];
    if (threadIdx.x == 1023) *ovf_cnt = 0;
}

// ---- phase 3: place edges into bucket segments via LDS cursors ----
__global__ __launch_bounds__(256) void k_scat3(const int* __restrict__ row,
                                               const int* __restrict__ col,
                                               const int* __restrict__ histT,
                                               const int* __restrict__ bstart,
                                               uint32* __restrict__ binned,
                                               int E, int B, int nb) {
    __shared__ int cur[NBMAX];
    const int b = blockIdx.x;
    for (int k = threadIdx.x; k < nb; k += 256)
        cur[k] = bstart[k] + histT[(size_t)k * B + b];
    __syncthreads();
    const int s = b * EB;
    const int e = (s + EB < E) ? s + EB : E;
    for (int i = s + threadIdx.x; i < e; i += 256) {
        int c = col[i];
        uint32 r = (uint32)row[i];
        int pos = atomicAdd(&cur[c >> 8], 1);       // LDS atomic
        binned[pos] = (r << 8) | (uint32)(c & 255);
    }
}

// ---- phase 4: per-bucket LDS ranks -> slots; fused deg + pre-scaled bf16 cast ----
__global__ __launch_bounds__(1024) void k_build(const int* __restrict__ bstart,
                                                const uint32* __restrict__ binned,
                                                const float2* __restrict__ x2,
                                                int* __restrict__ slots,
                                                int* __restrict__ deg,
                                                uint32* __restrict__ xb,
                                                int2* __restrict__ ovf,
                                                int* __restrict__ ovf_cnt,
                                                int n, int C) {
    __shared__ int cnt[256];
    __shared__ float sw[256];
    const int k = blockIdx.x;
    if (threadIdx.x < 256) cnt[threadIdx.x] = 0;
    __syncthreads();
    const int s = bstart[k], e = bstart[k + 1];
    const int base = k << 8;
    for (int i = s + threadIdx.x; i < e; i += 1024) {
        uint32 pk = binned[i];
        int cl = (int)(pk & 255);
        int r  = (int)(pk >> 8);
        int rk = atomicAdd(&cnt[cl], 1);            // LDS atomic
        int c  = base + cl;
        if (rk < C) {
            slots[(size_t)c * C + rk] = r;          // block-private window
        } else {
            int o = atomicAdd(ovf_cnt, 1);
            if (o < OVF_CAP) ovf[o] = make_int2(r, c);
        }
    }
    __syncthreads();
    if (threadIdx.x < 256) {
        int i = base + threadIdx.x;
        int d = cnt[threadIdx.x];
        sw[threadIdx.x] = dinv(d);
        if (i < n) deg[i] = d;
    }
    __syncthreads();
    // pre-scaled bf16 cast for this block's 256 nodes: xb = bf16(x * dis)
    // 256 nodes * 32 uint32 = 8192 elements
    for (int idx = threadIdx.x; idx < 256 * 32; idx += 1024) {
        int nl = idx >> 5;                          // node-local
        int i  = base + nl;
        if (i >= n) break;
        float w = sw[nl];
        float2 v = x2[(size_t)i * 32 + (idx & 31)];
        xb[(size_t)i * 32 + (idx & 31)] = pack_bf16x2(v.x * w, v.y * w);
    }
}

// ---- gather: one wave per node, 8 edges in parallel, uint4 loads, pure adds ----
// lane = (q, l): q = edge slot (lane>>3), l = feat octet (lane&7, feats 8l..8l+7)
__global__ void k_gather8(const uint32* __restrict__ xb,
                          const float4* __restrict__ x4,
                          const int* __restrict__ deg,
                          const int* __restrict__ slots,
                          const float* __restrict__ alpha_p,
                          const float* __restrict__ rs_p,
                          float4* __restrict__ out4, int n, int C) {
    int wid = (blockIdx.x * blockDim.x + threadIdx.x) >> 6;
    if (wid >= n) return;
    const int lane = threadIdx.x & 63;
    const int q = lane >> 3;
    const int l = lane & 7;
    int d = deg[wid];
    int e = (d < C) ? d : C;
    const int* sl = slots + (size_t)wid * C;
    float a0 = 0.f, a1 = 0.f, a2 = 0.f, a3 = 0.f;
    float a4 = 0.f, a5 = 0.f, a6 = 0.f, a7 = 0.f;
    int k = 0;
    for (; k + 16 <= e; k += 16) {                 // 16 edges/iter, 2 loads/lane
        int s0 = sl[k + q];
        int s1 = sl[k + 8 + q];
        uint4 p0 = ((const uint4*)(xb + (size_t)s0 * 32))[l];
        uint4 p1 = ((const uint4*)(xb + (size_t)s1 * 32))[l];
        a0 += blo(p0.x); a1 += bhi(p0.x); a2 += blo(p0.y); a3 += bhi(p0.y);
        a4 += blo(p0.z); a5 += bhi(p0.z); a6 += blo(p0.w); a7 += bhi(p0.w);
        a0 += blo(p1.x); a1 += bhi(p1.x); a2 += blo(p1.y); a3 += bhi(p1.y);
        a4 += blo(p1.z); a5 += bhi(p1.z); a6 += blo(p1.w); a7 += bhi(p1.w);
    }
    for (; k < e; k += 8) {                        // leftover edges
        int kk = k + q;
        if (kk < e) {
            int s0 = sl[kk];
            uint4 p0 = ((const uint4*)(xb + (size_t)s0 * 32))[l];
            a0 += blo(p0.x); a1 += bhi(p0.x); a2 += blo(p0.y); a3 += bhi(p0.y);
            a4 += blo(p0.z); a5 += bhi(p0.z); a6 += blo(p0.w); a7 += bhi(p0.w);
        }
    }
    // fold the 8 edge-slots: q0..7 -> q0
    #pragma unroll
    for (int off = 32; off >= 8; off >>= 1) {
        a0 += __shfl_down(a0, off, 64); a1 += __shfl_down(a1, off, 64);
        a2 += __shfl_down(a2, off, 64); a3 += __shfl_down(a3, off, 64);
        a4 += __shfl_down(a4, off, 64); a5 += __shfl_down(a5, off, 64);
        a6 += __shfl_down(a6, off, 64); a7 += __shfl_down(a7, off, 64);
    }
    if (q == 0) {
        float adw = (*alpha_p) * dinv(d);
        float rs  = *rs_p;
        size_t base = (size_t)wid * 16 + 2 * l;
        float4 xr0 = x4[base];
        float4 xr1 = x4[base + 1];
        float4 o0, o1;
        o0.x = fmaf(adw, a0, rs * xr0.x);
        o0.y = fmaf(adw, a1, rs * xr0.y);
        o0.z = fmaf(adw, a2, rs * xr0.z);
        o0.w = fmaf(adw, a3, rs * xr0.w);
        o1.x = fmaf(adw, a4, rs * xr1.x);
        o1.y = fmaf(adw, a5, rs * xr1.y);
        o1.z = fmaf(adw, a6, rs * xr1.z);
        o1.w = fmaf(adw, a7, rs * xr1.w);
        out4[base]     = o0;
        out4[base + 1] = o1;
    }
}

// ---- overflow fix-up (rare): fp32 exact ----
__global__ void k_ovf(const int2* __restrict__ ovf, const int* __restrict__ cnt_p,
                      const float* __restrict__ x, const int* __restrict__ deg,
                      const float* __restrict__ alpha_p, float* __restrict__ out) {
    int cnt = *cnt_p;
    if (cnt > OVF_CAP) cnt = OVF_CAP;
    if (cnt <= 0) return;
    float a = *alpha_p;
    long long total = (long long)cnt * 64;
    long long stride = (long long)gridDim.x * blockDim.x;
    for (long long idx = blockIdx.x * (long long)blockDim.x + threadIdx.x;
         idx < total; idx += stride) {
        int e = (int)(idx >> 6);
        int f = (int)(idx & 63);
        int2 rc = ovf[e];
        float w = a * dinv(deg[rc.x]) * dinv(deg[rc.y]);
        atomicAdd(&out[(size_t)rc.y * D_FEAT + f], w * x[(size_t)rc.x * D_FEAT + f]);
    }
}

// ================= fallback: direct padded-CSR build (global atomics) ========
__global__ void k_prep(const int* __restrict__ row, const int* __restrict__ col,
                       int* __restrict__ deg, int* __restrict__ slots,
                       int2* __restrict__ ovf, int* __restrict__ ovf_cnt,
                       int E, int C) {
    int t = blockIdx.x * blockDim.x + threadIdx.x;
    if (t < E) {
        int c = col[t];
        int r = row[t];
        int rk = atomicAdd(&deg[c], 1);
        if (rk < C) {
            slots[(size_t)c * C + rk] = r;
        } else {
            int o = atomicAdd(ovf_cnt, 1);
            if (o < OVF_CAP) ovf[o] = make_int2(r, c);
        }
    }
}
__global__ void k_cast(const float2* __restrict__ x2, const int* __restrict__ deg,
                       uint32* __restrict__ xb, int nhalf) {
    int t = blockIdx.x * blockDim.x + threadIdx.x;
    if (t < nhalf) {
        float w = dinv(deg[t >> 5]);
        float2 v = x2[t];
        xb[t] = pack_bf16x2(v.x * w, v.y * w);
    }
}

static inline char* align_up(char* p, size_t a) {
    return (char*)(((uintptr_t)p + (a - 1)) & ~(uintptr_t)(a - 1));
}

extern "C" void kernel_launch(void* const* d_in, const int* in_sizes, int n_in,
                              void* d_out, int out_size, void* d_ws, size_t ws_size,
                              hipStream_t stream) {
    const float* x         = (const float*)d_in[0];
    const float* alpha     = (const float*)d_in[1];
    const float* res_scale = (const float*)d_in[2];
    const int*   ei        = (const int*)d_in[3];

    const int n = in_sizes[0] / D_FEAT;      // 100000
    const int E = in_sizes[3] / 2;           // 1600000
    const int* row = ei;                     // sources
    const int* col = ei + E;                 // targets

    float* out = (float*)d_out;
    const int nhalf = n * (D_FEAT / 2);
    const int nb = (n + 255) >> 8;           // coarse buckets (256 nodes each)
    const int B  = (E + EB - 1) / EB;        // multisplit blocks

    // ---------- multisplit layout ----------
    {
        char* p = (char*)d_ws;
        int*    deg     = (int*)p;            p += (size_t)n * 4;
        int*    ovf_cnt = (int*)p;            p += 4;
        int2*   ovf     = (int2*)p;           p += (size_t)OVF_CAP * 8;
        int*    histT   = (int*)p;            p += (size_t)nb * B * 4;
        int*    total   = (int*)p;            p += (size_t)nb * 4;
        int*    bstart  = (int*)p;            p += (size_t)(nb + 1) * 4;
        p = align_up(p, 16);
        uint32* xb      = (uint32*)p;         p += (size_t)n * 128;
        uint32* binned  = (uint32*)p;         p += (size_t)E * 4;
        int*    slots   = (int*)p;
        const size_t fixed = (size_t)(p - (char*)d_ws);

        int C = 0;
        if (ws_size > fixed) {
            size_t c_avail = (ws_size - fixed) / ((size_t)n * 4);
            C = (c_avail > 32) ? 32 : (int)c_avail;
        }
        const bool ok = (C >= 16) && (nb <= NBMAX) && (B <= 512) &&
                        (n <= (NBMAX << 8));
        if (ok) {
            k_hist    <<<B, 256, 0, stream>>>(col, histT, E, B, nb);
            k_colscan <<<nb, 512, 0, stream>>>(histT, total, B);
            k_tinyscan<<<1, 1024, 0, stream>>>(total, bstart, ovf_cnt, nb);
            k_scat3   <<<B, 256, 0, stream>>>(row, col, histT, bstart, binned,
                                              E, B, nb);
            k_build   <<<nb, 1024, 0, stream>>>(bstart, binned, (const float2*)x,
                                                slots, deg, xb, ovf, ovf_cnt, n, C);
            const long long tt = (long long)n * D_FEAT;
            const int blocks = (int)((tt + 255) / 256);
            k_gather8<<<blocks, 256, 0, stream>>>(xb, (const float4*)x, deg, slots,
                                                  alpha, res_scale, (float4*)out,
                                                  n, C);
            k_ovf<<<64, 256, 0, stream>>>(ovf, ovf_cnt, x, deg, alpha, out);
            return;
        }
    }

    // ---------- fallback: direct padded CSR via global atomics ----------
    {
        char* p = (char*)d_ws;
        int*    deg     = (int*)p;            p += (size_t)n * 4;
        int*    ovf_cnt = (int*)p;            p += 4;
        int2*   ovf     = (int2*)p;           p += (size_t)OVF_CAP * 8;
        p = align_up(p, 16);
        uint32* xb      = (uint32*)p;         p += (size_t)n * 128;
        int*    slots   = (int*)p;
        const size_t fixed = (size_t)(p - (char*)d_ws);
        int C = 0;
        if (ws_size > fixed) {
            size_t c_avail = (ws_size - fixed) / ((size_t)n * 4);
            C = (c_avail > 32) ? 32 : (int)c_avail;
        }
        if (C < 1) return;
        hipMemsetAsync(deg, 0, (size_t)n * 4 + 4, stream);
        k_prep<<<(E + 255) / 256, 256, 0, stream>>>(row, col, deg, slots,
                                                    ovf, ovf_cnt, E, C);
        k_cast<<<(nhalf + 255) / 256, 256, 0, stream>>>((const float2*)x, deg,
                                                        xb, nhalf);
        const long long tt = (long long)n * D_FEAT;
        const int blocks = (int)((tt + 255) / 256);
        k_gather8<<<blocks, 256, 0, stream>>>(xb, (const float4*)x, deg, slots,
                                              alpha, res_scale, (float4*)out, n, C);
        k_ovf<<<64, 256, 0, stream>>>(ovf, ovf_cnt, x, deg, alpha, out);
    }
}